// Round 12
// baseline (544.259 us; speedup 1.0000x reference)
//
#include <hip/hip_runtime.h>
#include <hip/hip_bf16.h>
#include <math.h>

// Problem constants
#define NH   7        // hazards
#define NROW 16384    // B*S = 8*2048
#define DD   768      // hidden dim
#define KK   64       // bottleneck dim
#define THRG 0.05f

typedef float  f32x4   __attribute__((ext_vector_type(4)));
typedef __bf16 bf16x8  __attribute__((ext_vector_type(8)));
typedef short  short8v __attribute__((ext_vector_type(8)));
typedef short  short4v __attribute__((ext_vector_type(4)));

union V8 { short8v s; bf16x8 b; };

__device__ __forceinline__ float gate_of(const float* __restrict__ M, int s, int t) {
  float m = M[s * NH + t];
  return (s != t && fabsf(m) > THRG) ? m : 0.0f;
}

__device__ __forceinline__ float gelu_t(float v) {
  float u = 0.7978845608028654f * (v + 0.044715f * v * v * v);
  return v / (1.0f + __expf(-2.0f * u));   // v * sigmoid(2u)
}

// async 16B global -> LDS copy; lds ptr must be the WAVE-uniform base (HW adds lane*16)
__device__ __forceinline__ void gload_lds16(const void* g, void* l) {
  __builtin_amdgcn_global_load_lds(
      (const __attribute__((address_space(1))) unsigned int*)g,
      (__attribute__((address_space(3))) unsigned int*)l, 16, 0, 0);
}

// ---- prep: W1 [s][t][d][k] f32 -> W1P [pr][kc][kcol(64)][dl(64)] bf16,
// PRE-SWIZZLED (inverse of the LDS read XOR) for linear gload_lds. (R6-verified.)
__global__ void prep_w1(const float* __restrict__ W1, unsigned short* __restrict__ W1P) {
  int pr = blockIdx.x;                       // pr = s*7+t
  const float* src = W1 + (size_t)pr * DD * KK;
  __bf16* dst = (__bf16*)(W1P + (size_t)pr * 12 * 4096);
  for (int idx = threadIdx.x; idx < 12 * 4096; idx += blockDim.x) {
    int kc = idx >> 12, rem = idx & 4095;
    int kcol = rem >> 6, dl = rem & 63;
    int dl_log = dl ^ ((kcol & 7) << 3);     // elem-space inverse of byte XOR ((row&7)<<4)
    dst[idx] = (__bf16)src[(size_t)(kc * 64 + dl_log) * KK + kcol];
  }
}

// ---- prep: W2 [s][t][k][d] f32 -> W2P [(t*7+s)*6+nb][dloc(128)][k(64)] bf16, gate folded
__global__ void prep_w2(const float* __restrict__ M, const float* __restrict__ W2,
                        unsigned short* __restrict__ W2P) {
  int st = blockIdx.x;                       // st = s*7+t
  int s = st / NH, t = st % NH;
  float g = gate_of(M, s, t);
  const float* src = W2 + (size_t)st * KK * DD;
  __bf16* dst = (__bf16*)(W2P + (size_t)((t * NH + s) * 6) * 8192);
  for (int idx = threadIdx.x; idx < 6 * 128 * 64; idx += blockDim.x) {
    int nb = idx >> 13, rem = idx & 8191;
    int dloc = rem >> 6, k = rem & 63;
    dst[idx] = (__bf16)(g * src[(size_t)k * DD + nb * 128 + dloc]);
  }
}

// ---- prep: b2sum[t][d] = sum_s gate(s,t) * b2[s][t][d]
__global__ void prep_b2(const float* __restrict__ M, const float* __restrict__ b2,
                        float* __restrict__ b2sum) {
  int idx = blockIdx.x * blockDim.x + threadIdx.x;
  if (idx >= NH * DD) return;
  int t = idx / DD, d = idx % DD;
  float acc = 0.f;
  for (int s = 0; s < NH; ++s)
    acc += gate_of(M, s, t) * b2[(size_t)(s * NH + t) * DD + d];
  b2sum[idx] = acc;
}

// ---- Phase A (t-amortized, R9-verified, UNCHANGED): one block = one (s, rb, t-pair).
__global__ __launch_bounds__(256)
void chiA(const float* __restrict__ x, const float* __restrict__ M,
          const unsigned short* __restrict__ W1P, const float* __restrict__ b1,
          unsigned short* __restrict__ H) {
  __shared__ __align__(16) unsigned short xs[128 * 64];    // 16 KB, swizzled [xrow][d]
  __shared__ __align__(16) unsigned short w1s0[64 * 64];   //  8 KB, swizzled [kcol][d]
  __shared__ __align__(16) unsigned short w1s1[64 * 64];   //  8 KB

  int bid = (int)blockIdx.x;
  int nid = (bid & 7) * 448 + (bid >> 3);   // 3584 = 8*448; tg innermost -> x chunk reused
  int tg = nid & 3;  int rem = nid >> 2;    // rem = rb*7 + s
  int s = rem % NH, rb = rem / NH;
  int t0 = tg * 2, t1 = tg * 2 + 1;
  float g0 = gate_of(M, s, t0);
  float g1 = (t1 < NH) ? gate_of(M, s, t1) : 0.0f;
  bool a0 = (g0 != 0.0f), a1 = (g1 != 0.0f);
  if (!a0 && !a1) return;
  int pr0 = s * NH + t0, pr1 = s * NH + t1;
  int row0 = rb * 128;

  int tid = (int)threadIdx.x;
  int wid = tid >> 6, lane = tid & 63, l16 = lane & 15, l4 = lane >> 4;

  const f32x4 zero = {0.f, 0.f, 0.f, 0.f};
  f32x4 acc0[4][2], acc1[4][2];
#pragma unroll
  for (int m = 0; m < 4; ++m)
#pragma unroll
    for (int n = 0; n < 2; ++n) { acc0[m][n] = zero; acc1[m][n] = zero; }

  const float* xb = x + ((size_t)s * NROW + row0) * DD;
  const char* w1b0 = (const char*)(W1P + (size_t)pr0 * 12 * 4096);
  const char* w1b1 = (const char*)(W1P + (size_t)pr1 * 12 * 4096);

  for (int kc = 0; kc < 12; ++kc) {
    __syncthreads();   // protect LDS from previous step's readers
    if (a0) {
      const char* wsrc = w1b0 + (size_t)kc * 8192;
      char* wdst = (char*)w1s0 + (wid << 10);
#pragma unroll
      for (int r = 0; r < 2; ++r)
        gload_lds16(wsrc + r * 4096 + tid * 16, wdst + r * 4096);
    }
    if (a1) {
      const char* wsrc = w1b1 + (size_t)kc * 8192;
      char* wdst = (char*)w1s1 + (wid << 10);
#pragma unroll
      for (int r = 0; r < 2; ++r)
        gload_lds16(wsrc + r * 4096 + tid * 16, wdst + r * 4096);
    }
#pragma unroll
    for (int r = 0; r < 4; ++r) {
      int L = r * 4096 + tid * 16;          // byte offset in chunk
      int row = L >> 7, colB = L & 127;     // col = colB/2 (elems)
      const float* gp = xb + (size_t)row * DD + kc * 64 + (colB >> 1);
      f32x4 v0 = *(const f32x4*)gp;
      f32x4 v1 = *(const f32x4*)(gp + 4);
      bf16x8 sv;
      sv[0] = (__bf16)v0[0]; sv[1] = (__bf16)v0[1];
      sv[2] = (__bf16)v0[2]; sv[3] = (__bf16)v0[3];
      sv[4] = (__bf16)v1[0]; sv[5] = (__bf16)v1[1];
      sv[6] = (__bf16)v1[2]; sv[7] = (__bf16)v1[3];
      *(bf16x8*)((char*)xs + (L ^ ((row & 7) << 4))) = sv;
    }
    __syncthreads();   // drains vmcnt (gload_lds) + lgkm (ds_writes)

    V8 bf2[2][2];
#pragma unroll
    for (int nn = 0; nn < 2; ++nn)
#pragma unroll
      for (int k2 = 0; k2 < 2; ++k2) {
        int xr = wid * 32 + nn * 16 + l16;
        int byte = (xr * 128 + k2 * 64 + l4 * 16) ^ ((xr & 7) << 4);
        bf2[nn][k2].s = *(const short8v*)((const char*)xs + byte);
      }
    if (a0) {
      V8 af[4][2];
#pragma unroll
      for (int mm = 0; mm < 4; ++mm)
#pragma unroll
        for (int k2 = 0; k2 < 2; ++k2) {
          int rowl = mm * 16 + l16;
          int byte = (rowl * 128 + k2 * 64 + l4 * 16) ^ ((rowl & 7) << 4);
          af[mm][k2].s = *(const short8v*)((const char*)w1s0 + byte);
        }
#pragma unroll
      for (int k2 = 0; k2 < 2; ++k2)
#pragma unroll
        for (int mm = 0; mm < 4; ++mm)
#pragma unroll
          for (int nn = 0; nn < 2; ++nn)
            acc0[mm][nn] = __builtin_amdgcn_mfma_f32_16x16x32_bf16(af[mm][k2].b, bf2[nn][k2].b, acc0[mm][nn], 0, 0, 0);
    }
    if (a1) {
      V8 af[4][2];
#pragma unroll
      for (int mm = 0; mm < 4; ++mm)
#pragma unroll
        for (int k2 = 0; k2 < 2; ++k2) {
          int rowl = mm * 16 + l16;
          int byte = (rowl * 128 + k2 * 64 + l4 * 16) ^ ((rowl & 7) << 4);
          af[mm][k2].s = *(const short8v*)((const char*)w1s1 + byte);
        }
#pragma unroll
      for (int k2 = 0; k2 < 2; ++k2)
#pragma unroll
        for (int mm = 0; mm < 4; ++mm)
#pragma unroll
          for (int nn = 0; nn < 2; ++nn)
            acc1[mm][nn] = __builtin_amdgcn_mfma_f32_16x16x32_bf16(af[mm][k2].b, bf2[nn][k2].b, acc1[mm][nn], 0, 0, 0);
    }
  }

  if (a0) {
#pragma unroll
    for (int mm = 0; mm < 4; ++mm) {
      f32x4 bv = *(const f32x4*)(b1 + (size_t)pr0 * KK + mm * 16 + l4 * 4);
#pragma unroll
      for (int nn = 0; nn < 2; ++nn) {
        union { short4v s4; __bf16 b4[4]; } o;
#pragma unroll
        for (int r = 0; r < 4; ++r) o.b4[r] = (__bf16)gelu_t(acc0[mm][nn][r] + bv[r]);
        int xrow = row0 + wid * 32 + nn * 16 + l16;
        unsigned short* hp = H + ((size_t)pr0 * NROW + xrow) * KK + mm * 16 + l4 * 4;
        *(short4v*)hp = o.s4;
      }
    }
  }
  if (a1) {
#pragma unroll
    for (int mm = 0; mm < 4; ++mm) {
      f32x4 bv = *(const f32x4*)(b1 + (size_t)pr1 * KK + mm * 16 + l4 * 4);
#pragma unroll
      for (int nn = 0; nn < 2; ++nn) {
        union { short4v s4; __bf16 b4[4]; } o;
#pragma unroll
        for (int r = 0; r < 4; ++r) o.b4[r] = (__bf16)gelu_t(acc1[mm][nn][r] + bv[r]);
        int xrow = row0 + wid * 32 + nn * 16 + l16;
        unsigned short* hp = H + ((size_t)pr1 * NROW + xrow) * KK + mm * 16 + l4 * 4;
        *(short4v*)hp = o.s4;
      }
    }
  }
}

// ---- Phase B: R9's 256-thread/128x128 shape (205us verified), minus the w2s LDS
// round-trip: A-fragments load DIRECTLY from L2-resident W2P (4.8 MB, re-read by
// 128 rb-blocks -> L2-hot; the fragment address pattern needs no cross-lane repack).
// The 8 af loads are issued at the top of the s-step — no LDS dependency — so their
// L2 latency hides under hs staging + barrier. LDS halves to 16 KB; per-step
// staging work halves.
__global__ __launch_bounds__(256)
void chiB(const unsigned short* __restrict__ H, const float* __restrict__ x,
          const float* __restrict__ M, const unsigned short* __restrict__ W2P,
          const float* __restrict__ b2sum, float* __restrict__ out) {
  __shared__ __align__(16) unsigned short hs[128 * 64];   // 16 KB, swizzled [row][k]

  int bid = (int)blockIdx.x;
  int nid = (bid & 7) * 672 + (bid >> 3);   // 5376 = 8*672; nb innermost -> L2 reuse of H chunk
  int nb = nid % 6, rem = nid / 6;
  int rb = rem % 128, t = rem / 128;
  int row0 = rb * 128, col0 = nb * 128;

  int tid = (int)threadIdx.x;
  int wid = tid >> 6, lane = tid & 63, l16 = lane & 15, l4 = lane >> 4;
  int wr = wid & 1, wc = wid >> 1;          // wave = 64 rows x 64 cols of the 128x128 tile

  const f32x4 zero = {0.f, 0.f, 0.f, 0.f};
  f32x4 acc[4][4];                          // [m]=col tiles, [n]=row tiles
#pragma unroll
  for (int m = 0; m < 4; ++m)
#pragma unroll
    for (int n = 0; n < 4; ++n) acc[m][n] = zero;

  for (int s = 0; s < NH; ++s) {
    if (gate_of(M, s, t) == 0.0f) continue;

    // A-fragments: direct from L2-resident W2P, issued FIRST (no LDS dependency)
    const char* wb = (const char*)(W2P + (size_t)((t * NH + s) * 6 + nb) * 8192);
    V8 af[4][2];
#pragma unroll
    for (int m = 0; m < 4; ++m)
#pragma unroll
      for (int k2 = 0; k2 < 2; ++k2) {
        int dl = wc * 64 + m * 16 + l16;
        af[m][k2].s = *(const short8v*)(wb + dl * 128 + k2 * 64 + l4 * 16);
      }

    __syncthreads();   // protect hs from previous step's readers
    const char* hb = (const char*)(H + ((size_t)(s * NH + t) * NROW + row0) * KK);
#pragma unroll
    for (int r = 0; r < 4; ++r) {
      int L = r * 4096 + tid * 16;
      int row = L >> 7;
      short8v v = *(const short8v*)(hb + L);
      *(short8v*)((char*)hs + (L ^ ((row & 7) << 4))) = v;
    }
    __syncthreads();

    V8 bfr[4][2];
#pragma unroll
    for (int n = 0; n < 4; ++n)                 // B: H rows (output rows)
#pragma unroll
      for (int k2 = 0; k2 < 2; ++k2) {
        int rl = wr * 64 + n * 16 + l16;
        int byte = (rl * 128 + k2 * 64 + l4 * 16) ^ ((rl & 7) << 4);
        bfr[n][k2].s = *(const short8v*)((const char*)hs + byte);
      }
#pragma unroll
    for (int k2 = 0; k2 < 2; ++k2)
#pragma unroll
      for (int m = 0; m < 4; ++m)
#pragma unroll
        for (int n = 0; n < 4; ++n)
          acc[m][n] = __builtin_amdgcn_mfma_f32_16x16x32_bf16(af[m][k2].b, bfr[n][k2].b, acc[m][n], 0, 0, 0);
  }

  // epilogue: + x residual (exact f32) + b2sum; coalesced f32x4 along columns
#pragma unroll
  for (int m = 0; m < 4; ++m) {
    int col = col0 + wc * 64 + m * 16 + l4 * 4;
    f32x4 bv = *(const f32x4*)(b2sum + (size_t)t * DD + col);
#pragma unroll
    for (int n = 0; n < 4; ++n) {
      int row = row0 + wr * 64 + n * 16 + l16;
      size_t off = ((size_t)t * NROW + row) * DD + col;
      f32x4 xv = *(const f32x4*)(x + off);
      f32x4 ov;
#pragma unroll
      for (int r = 0; r < 4; ++r) ov[r] = acc[m][n][r] + xv[r] + bv[r];
      *(f32x4*)(out + off) = ov;
    }
  }
}

extern "C" void kernel_launch(void* const* d_in, const int* in_sizes, int n_in,
                              void* d_out, int out_size, void* d_ws, size_t ws_size,
                              hipStream_t stream) {
  const float* x  = (const float*)d_in[0];
  const float* M  = (const float*)d_in[1];
  const float* W1 = (const float*)d_in[2];
  const float* b1 = (const float*)d_in[3];
  const float* W2 = (const float*)d_in[4];
  const float* b2 = (const float*)d_in[5];
  float* out = (float*)d_out;

  char* ws = (char*)d_ws;
  unsigned short* W1P = (unsigned short*)ws;                         // 4,816,896 B
  unsigned short* W2P = (unsigned short*)(ws + 4816896);             // 4,816,896 B
  float* b2sum        = (float*)(ws + 9633792);                      // 21,504 B
  unsigned short* H   = (unsigned short*)(ws + 9655296);             // 102,760,448 B

  prep_w1<<<dim3(49), dim3(256), 0, stream>>>(W1, W1P);
  prep_w2<<<dim3(49), dim3(256), 0, stream>>>(M, W2, W2P);
  prep_b2<<<dim3((NH * DD + 255) / 256), dim3(256), 0, stream>>>(M, b2, b2sum);
  chiA<<<dim3(3584), dim3(256), 0, stream>>>(x, M, W1P, b1, H);
  chiB<<<dim3(5376), dim3(256), 0, stream>>>(H, x, M, W2P, b2sum, out);
}

// Round 13
// 445.828 us; speedup vs baseline: 1.2208x; 1.2208x over previous
//
#include <hip/hip_runtime.h>
#include <hip/hip_bf16.h>
#include <math.h>

// Problem constants
#define NH   7        // hazards
#define NROW 16384    // B*S = 8*2048
#define DD   768      // hidden dim
#define KK   64       // bottleneck dim
#define THRG 0.05f

typedef float  f32x4   __attribute__((ext_vector_type(4)));
typedef __bf16 bf16x8  __attribute__((ext_vector_type(8)));
typedef short  short8v __attribute__((ext_vector_type(8)));
typedef short  short4v __attribute__((ext_vector_type(4)));

union V8 { short8v s; bf16x8 b; };

__device__ __forceinline__ float gate_of(const float* __restrict__ M, int s, int t) {
  float m = M[s * NH + t];
  return (s != t && fabsf(m) > THRG) ? m : 0.0f;
}

__device__ __forceinline__ float gelu_t(float v) {
  float u = 0.7978845608028654f * (v + 0.044715f * v * v * v);
  return v / (1.0f + __expf(-2.0f * u));   // v * sigmoid(2u)
}

// async 16B global -> LDS copy; lds ptr must be the WAVE-uniform base (HW adds lane*16)
__device__ __forceinline__ void gload_lds16(const void* g, void* l) {
  __builtin_amdgcn_global_load_lds(
      (const __attribute__((address_space(1))) unsigned int*)g,
      (__attribute__((address_space(3))) unsigned int*)l, 16, 0, 0);
}

// ---- prep: W1 [s][t][d][k] f32 -> W1P [pr][kc][kcol(64)][dl(64)] bf16,
// PRE-SWIZZLED (inverse of the LDS read XOR) for linear gload_lds. (R6-verified.)
__global__ void prep_w1(const float* __restrict__ W1, unsigned short* __restrict__ W1P) {
  int pr = blockIdx.x;                       // pr = s*7+t
  const float* src = W1 + (size_t)pr * DD * KK;
  __bf16* dst = (__bf16*)(W1P + (size_t)pr * 12 * 4096);
  for (int idx = threadIdx.x; idx < 12 * 4096; idx += blockDim.x) {
    int kc = idx >> 12, rem = idx & 4095;
    int kcol = rem >> 6, dl = rem & 63;
    int dl_log = dl ^ ((kcol & 7) << 3);     // elem-space inverse of byte XOR ((row&7)<<4)
    dst[idx] = (__bf16)src[(size_t)(kc * 64 + dl_log) * KK + kcol];
  }
}

// ---- prep: W2 [s][t][k][d] f32 -> W2P [(t*7+s)*6+nb][dloc(128)][k(64)] bf16, gate folded
__global__ void prep_w2(const float* __restrict__ M, const float* __restrict__ W2,
                        unsigned short* __restrict__ W2P) {
  int st = blockIdx.x;                       // st = s*7+t
  int s = st / NH, t = st % NH;
  float g = gate_of(M, s, t);
  const float* src = W2 + (size_t)st * KK * DD;
  __bf16* dst = (__bf16*)(W2P + (size_t)((t * NH + s) * 6) * 8192);
  for (int idx = threadIdx.x; idx < 6 * 128 * 64; idx += blockDim.x) {
    int nb = idx >> 13, rem = idx & 8191;
    int dloc = rem >> 6, k = rem & 63;
    dst[idx] = (__bf16)(g * src[(size_t)k * DD + nb * 128 + dloc]);
  }
}

// ---- prep: b2sum[t][d] = sum_s gate(s,t) * b2[s][t][d]
__global__ void prep_b2(const float* __restrict__ M, const float* __restrict__ b2,
                        float* __restrict__ b2sum) {
  int idx = blockIdx.x * blockDim.x + threadIdx.x;
  if (idx >= NH * DD) return;
  int t = idx / DD, d = idx % DD;
  float acc = 0.f;
  for (int s = 0; s < NH; ++s)
    acc += gate_of(M, s, t) * b2[(size_t)(s * NH + t) * DD + d];
  b2sum[idx] = acc;
}

// ---- Phase A (t-amortized, R9-verified): one block = one (s, rb, t-pair). x is
// staged ONCE per step and consumed by up to TWO targets (separate W1 buffers +
// accumulators, shared B-fragments). Gating is block-uniform; barriers outside.
__global__ __launch_bounds__(256)
void chiA(const float* __restrict__ x, const float* __restrict__ M,
          const unsigned short* __restrict__ W1P, const float* __restrict__ b1,
          unsigned short* __restrict__ H) {
  __shared__ __align__(16) unsigned short xs[128 * 64];    // 16 KB, swizzled [xrow][d]
  __shared__ __align__(16) unsigned short w1s0[64 * 64];   //  8 KB, swizzled [kcol][d]
  __shared__ __align__(16) unsigned short w1s1[64 * 64];   //  8 KB

  int bid = (int)blockIdx.x;
  int nid = (bid & 7) * 448 + (bid >> 3);   // 3584 = 8*448; tg innermost -> x chunk reused
  int tg = nid & 3;  int rem = nid >> 2;    // rem = rb*7 + s
  int s = rem % NH, rb = rem / NH;
  int t0 = tg * 2, t1 = tg * 2 + 1;
  float g0 = gate_of(M, s, t0);
  float g1 = (t1 < NH) ? gate_of(M, s, t1) : 0.0f;
  bool a0 = (g0 != 0.0f), a1 = (g1 != 0.0f);
  if (!a0 && !a1) return;
  int pr0 = s * NH + t0, pr1 = s * NH + t1;
  int row0 = rb * 128;

  int tid = (int)threadIdx.x;
  int wid = tid >> 6, lane = tid & 63, l16 = lane & 15, l4 = lane >> 4;

  const f32x4 zero = {0.f, 0.f, 0.f, 0.f};
  f32x4 acc0[4][2], acc1[4][2];
#pragma unroll
  for (int m = 0; m < 4; ++m)
#pragma unroll
    for (int n = 0; n < 2; ++n) { acc0[m][n] = zero; acc1[m][n] = zero; }

  const float* xb = x + ((size_t)s * NROW + row0) * DD;
  const char* w1b0 = (const char*)(W1P + (size_t)pr0 * 12 * 4096);
  const char* w1b1 = (const char*)(W1P + (size_t)pr1 * 12 * 4096);

  for (int kc = 0; kc < 12; ++kc) {
    __syncthreads();   // protect LDS from previous step's readers
    if (a0) {
      const char* wsrc = w1b0 + (size_t)kc * 8192;
      char* wdst = (char*)w1s0 + (wid << 10);
#pragma unroll
      for (int r = 0; r < 2; ++r)
        gload_lds16(wsrc + r * 4096 + tid * 16, wdst + r * 4096);
    }
    if (a1) {
      const char* wsrc = w1b1 + (size_t)kc * 8192;
      char* wdst = (char*)w1s1 + (wid << 10);
#pragma unroll
      for (int r = 0; r < 2; ++r)
        gload_lds16(wsrc + r * 4096 + tid * 16, wdst + r * 4096);
    }
#pragma unroll
    for (int r = 0; r < 4; ++r) {
      int L = r * 4096 + tid * 16;          // byte offset in chunk
      int row = L >> 7, colB = L & 127;     // col = colB/2 (elems)
      const float* gp = xb + (size_t)row * DD + kc * 64 + (colB >> 1);
      f32x4 v0 = *(const f32x4*)gp;
      f32x4 v1 = *(const f32x4*)(gp + 4);
      bf16x8 sv;
      sv[0] = (__bf16)v0[0]; sv[1] = (__bf16)v0[1];
      sv[2] = (__bf16)v0[2]; sv[3] = (__bf16)v0[3];
      sv[4] = (__bf16)v1[0]; sv[5] = (__bf16)v1[1];
      sv[6] = (__bf16)v1[2]; sv[7] = (__bf16)v1[3];
      *(bf16x8*)((char*)xs + (L ^ ((row & 7) << 4))) = sv;
    }
    __syncthreads();   // drains vmcnt (gload_lds) + lgkm (ds_writes)

    V8 bf2[2][2];
#pragma unroll
    for (int nn = 0; nn < 2; ++nn)
#pragma unroll
      for (int k2 = 0; k2 < 2; ++k2) {
        int xr = wid * 32 + nn * 16 + l16;
        int byte = (xr * 128 + k2 * 64 + l4 * 16) ^ ((xr & 7) << 4);
        bf2[nn][k2].s = *(const short8v*)((const char*)xs + byte);
      }
    if (a0) {
      V8 af[4][2];
#pragma unroll
      for (int mm = 0; mm < 4; ++mm)
#pragma unroll
        for (int k2 = 0; k2 < 2; ++k2) {
          int rowl = mm * 16 + l16;
          int byte = (rowl * 128 + k2 * 64 + l4 * 16) ^ ((rowl & 7) << 4);
          af[mm][k2].s = *(const short8v*)((const char*)w1s0 + byte);
        }
#pragma unroll
      for (int k2 = 0; k2 < 2; ++k2)
#pragma unroll
        for (int mm = 0; mm < 4; ++mm)
#pragma unroll
          for (int nn = 0; nn < 2; ++nn)
            acc0[mm][nn] = __builtin_amdgcn_mfma_f32_16x16x32_bf16(af[mm][k2].b, bf2[nn][k2].b, acc0[mm][nn], 0, 0, 0);
    }
    if (a1) {
      V8 af[4][2];
#pragma unroll
      for (int mm = 0; mm < 4; ++mm)
#pragma unroll
        for (int k2 = 0; k2 < 2; ++k2) {
          int rowl = mm * 16 + l16;
          int byte = (rowl * 128 + k2 * 64 + l4 * 16) ^ ((rowl & 7) << 4);
          af[mm][k2].s = *(const short8v*)((const char*)w1s1 + byte);
        }
#pragma unroll
      for (int k2 = 0; k2 < 2; ++k2)
#pragma unroll
        for (int mm = 0; mm < 4; ++mm)
#pragma unroll
          for (int nn = 0; nn < 2; ++nn)
            acc1[mm][nn] = __builtin_amdgcn_mfma_f32_16x16x32_bf16(af[mm][k2].b, bf2[nn][k2].b, acc1[mm][nn], 0, 0, 0);
    }
  }

  if (a0) {
#pragma unroll
    for (int mm = 0; mm < 4; ++mm) {
      f32x4 bv = *(const f32x4*)(b1 + (size_t)pr0 * KK + mm * 16 + l4 * 4);
#pragma unroll
      for (int nn = 0; nn < 2; ++nn) {
        union { short4v s4; __bf16 b4[4]; } o;
#pragma unroll
        for (int r = 0; r < 4; ++r) o.b4[r] = (__bf16)gelu_t(acc0[mm][nn][r] + bv[r]);
        int xrow = row0 + wid * 32 + nn * 16 + l16;
        unsigned short* hp = H + ((size_t)pr0 * NROW + xrow) * KK + mm * 16 + l4 * 4;
        *(short4v*)hp = o.s4;
      }
    }
  }
  if (a1) {
#pragma unroll
    for (int mm = 0; mm < 4; ++mm) {
      f32x4 bv = *(const f32x4*)(b1 + (size_t)pr1 * KK + mm * 16 + l4 * 4);
#pragma unroll
      for (int nn = 0; nn < 2; ++nn) {
        union { short4v s4; __bf16 b4[4]; } o;
#pragma unroll
        for (int r = 0; r < 4; ++r) o.b4[r] = (__bf16)gelu_t(acc1[mm][nn][r] + bv[r]);
        int xrow = row0 + wid * 32 + nn * 16 + l16;
        unsigned short* hp = H + ((size_t)pr1 * NROW + xrow) * KK + mm * 16 + l4 * 4;
        *(short4v*)hp = o.s4;
      }
    }
  }
}

// ---- Phase B: out[t] = x[t] + sum_s H[s,t](128xK) * W2P[t,s](Kx128) + b2sum[t]
// R9's measured 205us variant, byte-identical: hs + w2s LDS staging (cooperative
// broadcast of W2 keeps L2 traffic at 1/4 wave cost — R12 proved removing it
// regresses), 2 barriers/source, SWAPPED operands (A = w2s dloc rows, B = hs rows)
// so the D-frag's 4 regs run along output columns -> coalesced f32x4 stores.
__global__ __launch_bounds__(256, 4)
void chiB(const unsigned short* __restrict__ H, const float* __restrict__ x,
          const float* __restrict__ M, const unsigned short* __restrict__ W2P,
          const float* __restrict__ b2sum, float* __restrict__ out) {
  __shared__ __align__(16) unsigned short hs[128 * 64];   // 16 KB, swizzled [row][k]
  __shared__ __align__(16) unsigned short w2s[128 * 64];  // 16 KB, swizzled [dloc][k]

  int bid = (int)blockIdx.x;
  int nid = (bid & 7) * 672 + (bid >> 3);   // 5376 = 8*672; nb innermost -> L2 reuse of H chunk
  int nb = nid % 6, rem = nid / 6;
  int rb = rem % 128, t = rem / 128;
  int row0 = rb * 128, col0 = nb * 128;

  int tid = (int)threadIdx.x;
  int wid = tid >> 6, lane = tid & 63, l16 = lane & 15, l4 = lane >> 4;
  int wr = wid & 1, wc = wid >> 1;          // wave = 64 rows x 64 cols of the 128x128 tile

  const f32x4 zero = {0.f, 0.f, 0.f, 0.f};
  f32x4 acc[4][4];                          // [m]=col tiles, [n]=row tiles
#pragma unroll
  for (int m = 0; m < 4; ++m)
#pragma unroll
    for (int n = 0; n < 4; ++n) acc[m][n] = zero;

  for (int s = 0; s < NH; ++s) {
    if (gate_of(M, s, t) == 0.0f) continue;
    __syncthreads();   // protect LDS from previous step's readers
    const char* hb = (const char*)(H + ((size_t)(s * NH + t) * NROW + row0) * KK);
    const char* wb = (const char*)(W2P + (size_t)((t * NH + s) * 6 + nb) * 8192);
#pragma unroll
    for (int r = 0; r < 4; ++r) {
      int L = r * 4096 + tid * 16;
      int row = L >> 7;
      short8v v = *(const short8v*)(hb + L);
      *(short8v*)((char*)hs + (L ^ ((row & 7) << 4))) = v;
      short8v w = *(const short8v*)(wb + L);
      *(short8v*)((char*)w2s + (L ^ ((row & 7) << 4))) = w;
    }
    __syncthreads();

    V8 af[4][2], bfr[4][2];
#pragma unroll
    for (int m = 0; m < 4; ++m)                 // A: W2 dloc rows (output columns)
#pragma unroll
      for (int k2 = 0; k2 < 2; ++k2) {
        int dl = wc * 64 + m * 16 + l16;
        int byte = (dl * 128 + k2 * 64 + l4 * 16) ^ ((dl & 7) << 4);
        af[m][k2].s = *(const short8v*)((const char*)w2s + byte);
      }
#pragma unroll
    for (int n = 0; n < 4; ++n)                 // B: H rows (output rows)
#pragma unroll
      for (int k2 = 0; k2 < 2; ++k2) {
        int rl = wr * 64 + n * 16 + l16;
        int byte = (rl * 128 + k2 * 64 + l4 * 16) ^ ((rl & 7) << 4);
        bfr[n][k2].s = *(const short8v*)((const char*)hs + byte);
      }
#pragma unroll
    for (int k2 = 0; k2 < 2; ++k2)
#pragma unroll
      for (int m = 0; m < 4; ++m)
#pragma unroll
        for (int n = 0; n < 4; ++n)
          acc[m][n] = __builtin_amdgcn_mfma_f32_16x16x32_bf16(af[m][k2].b, bfr[n][k2].b, acc[m][n], 0, 0, 0);
  }

  // epilogue: + x residual (exact f32) + b2sum; coalesced f32x4 along columns
#pragma unroll
  for (int m = 0; m < 4; ++m) {
    int col = col0 + wc * 64 + m * 16 + l4 * 4;
    f32x4 bv = *(const f32x4*)(b2sum + (size_t)t * DD + col);
#pragma unroll
    for (int n = 0; n < 4; ++n) {
      int row = row0 + wr * 64 + n * 16 + l16;
      size_t off = ((size_t)t * NROW + row) * DD + col;
      f32x4 xv = *(const f32x4*)(x + off);
      f32x4 ov;
#pragma unroll
      for (int r = 0; r < 4; ++r) ov[r] = acc[m][n][r] + xv[r] + bv[r];
      *(f32x4*)(out + off) = ov;
    }
  }
}

extern "C" void kernel_launch(void* const* d_in, const int* in_sizes, int n_in,
                              void* d_out, int out_size, void* d_ws, size_t ws_size,
                              hipStream_t stream) {
  const float* x  = (const float*)d_in[0];
  const float* M  = (const float*)d_in[1];
  const float* W1 = (const float*)d_in[2];
  const float* b1 = (const float*)d_in[3];
  const float* W2 = (const float*)d_in[4];
  const float* b2 = (const float*)d_in[5];
  float* out = (float*)d_out;

  char* ws = (char*)d_ws;
  unsigned short* W1P = (unsigned short*)ws;                         // 4,816,896 B
  unsigned short* W2P = (unsigned short*)(ws + 4816896);             // 4,816,896 B
  float* b2sum        = (float*)(ws + 9633792);                      // 21,504 B
  unsigned short* H   = (unsigned short*)(ws + 9655296);             // 102,760,448 B

  prep_w1<<<dim3(49), dim3(256), 0, stream>>>(W1, W1P);
  prep_w2<<<dim3(49), dim3(256), 0, stream>>>(M, W2, W2P);
  prep_b2<<<dim3((NH * DD + 255) / 256), dim3(256), 0, stream>>>(M, b2, b2sum);
  chiA<<<dim3(3584), dim3(256), 0, stream>>>(x, M, W1P, b1, H);
  chiB<<<dim3(5376), dim3(256), 0, stream>>>(H, x, M, W2P, b2sum, out);
}